// Round 1
// baseline (95.203 us; speedup 1.0000x reference)
//
#include <hip/hip_runtime.h>
#include <hip/hip_bf16.h>

#define NB 32
#define NN 1024
#define FF 128

typedef __attribute__((ext_vector_type(8))) short short8;
typedef __attribute__((ext_vector_type(4))) float f32x4;

static __device__ __forceinline__ unsigned short f2bf(float x) {
  unsigned int u = __float_as_uint(x);
  u += 0x7fffu + ((u >> 16) & 1u);
  return (unsigned short)(u >> 16);
}

static __device__ __forceinline__ unsigned long long pack4bf(float a, float b, float c, float d) {
  return (unsigned long long)f2bf(a)
       | ((unsigned long long)f2bf(b) << 16)
       | ((unsigned long long)f2bf(c) << 32)
       | ((unsigned long long)f2bf(d) << 48);
}

// ---------------- k1: partial column sums of A (d[b,j] = 1 + sum_i A[b,i,j]) ----
__global__ void k1_colsum(const float* __restrict__ A, float* __restrict__ partial) {
  int j = blockIdx.x * 256 + threadIdx.x;   // 0..1023
  int s = blockIdx.y;                        // 0..7  (i-chunk)
  int b = blockIdx.z;                        // 0..31
  const float* p = A + (size_t)b * NN * NN + (size_t)(s * 128) * NN + j;
  float sum = 0.f;
  #pragma unroll 4
  for (int i = 0; i < 128; ++i) sum += p[(size_t)i * NN];
  partial[((b * 8 + s) << 10) + j] = sum;
}

// ---------------- k2: inv_sqrt_d, zero pooled, Wt = bf16(W^T) -------------------
__global__ void k2_finalize(const float* __restrict__ partial, const float* __restrict__ W,
                            float* __restrict__ isd, float* __restrict__ pooled,
                            unsigned short* __restrict__ Wt) {
  int idx = blockIdx.x * 256 + threadIdx.x;  // 0..32767
  int b = idx >> 10, j = idx & 1023;
  float d = 1.0f;
  #pragma unroll
  for (int s = 0; s < 8; ++s) d += partial[((b * 8 + s) << 10) + j];
  isd[idx] = rsqrtf(d);
  if (idx < 4096) pooled[idx] = 0.f;
  if (idx < 16384) {
    int o = idx >> 7, k = idx & 127;
    Wt[idx] = f2bf(W[k * FF + o]);   // Wt[o][k] = W[k][o]
  }
}

// ---------------- k3: HWpT[b][o][j] = bf16( isd[b,j] * sum_k W[k][o]*H[b][j][k] )
// MFMA with A-operand = Wt (o x k), B-operand = H (j as n, k contiguous) -> D[o][j]
__global__ __launch_bounds__(512) void k3_hw(const float* __restrict__ H,
                                             const unsigned short* __restrict__ Wt,
                                             const float* __restrict__ isd,
                                             unsigned short* __restrict__ HWpT) {
  __shared__ unsigned short Ws[128][136];
  __shared__ unsigned short Hs[128][136];
  int jblk = blockIdx.x;  // 0..7
  int b = blockIdx.y;     // 0..31
  int tid = threadIdx.x, wave = tid >> 6, lane = tid & 63;

  // stage Wt (bf16, 128x128)
  {
    int r = tid >> 4, c = (tid & 15) << 3;
    #pragma unroll
    for (int p = 0; p < 4; ++p) {
      int row = r + (p << 5);
      *reinterpret_cast<short8*>(&Ws[row][c]) =
          *reinterpret_cast<const short8*>(Wt + row * FF + c);
    }
  }
  // stage H tile (fp32 -> bf16), rows j, k contiguous
  {
    int r = tid >> 5, c = (tid & 31) << 2;
    const float* Hbase = H + (size_t)b * NN * FF + (size_t)(jblk * 128) * FF;
    #pragma unroll
    for (int p = 0; p < 8; ++p) {
      int row = r + (p << 4);
      const float4 v = *reinterpret_cast<const float4*>(Hbase + (size_t)row * FF + c);
      *reinterpret_cast<unsigned long long*>(&Hs[row][c]) = pack4bf(v.x, v.y, v.z, v.w);
    }
  }
  __syncthreads();

  f32x4 acc[8];
  #pragma unroll
  for (int i = 0; i < 8; ++i) acc[i] = (f32x4){0.f, 0.f, 0.f, 0.f};

  int mrow = (wave << 4) + (lane & 15);
  int koff = (lane >> 4) << 3;
  #pragma unroll
  for (int kk = 0; kk < 4; ++kk) {
    short8 af = *reinterpret_cast<const short8*>(&Ws[mrow][(kk << 5) + koff]);
    #pragma unroll
    for (int nf = 0; nf < 8; ++nf) {
      short8 bf = *reinterpret_cast<const short8*>(&Hs[(nf << 4) + (lane & 15)][(kk << 5) + koff]);
      acc[nf] = __builtin_amdgcn_mfma_f32_16x16x32_bf16(af, bf, acc[nf], 0, 0, 0);
    }
  }

  // epilogue: scale columns j by isd, store transposed (o-major)
  int fbase = (wave << 4) + ((lane >> 4) << 2);
  #pragma unroll
  for (int nf = 0; nf < 8; ++nf) {
    int j = (jblk << 7) + (nf << 4) + (lane & 15);
    float sc = isd[(b << 10) + j];
    size_t outb = (size_t)b * FF * NN + (size_t)j;
    #pragma unroll
    for (int r = 0; r < 4; ++r) {
      HWpT[outb + (size_t)(fbase + r) * NN] = f2bf(acc[nf][r] * sc);
    }
  }
}

// ---------------- k4: big GEMM  h = relu(isd_i * (Atilde @ HWp')[i,f] + bias_f),
// fused node-sum pooling -> atomicAdd into pooled[b][f]
__global__ __launch_bounds__(256) void k4_gcn(const float* __restrict__ A,
                                              const unsigned short* __restrict__ HWpT,
                                              const float* __restrict__ isd,
                                              const float* __restrict__ bias,
                                              float* __restrict__ pooled) {
  __shared__ unsigned short As[64][72];    // i rows x k(=j) cols, bf16
  __shared__ unsigned short Bs[128][72];   // f rows x k(=j) cols, bf16
  int iblk = blockIdx.x;  // 0..15
  int b = blockIdx.y;     // 0..31
  int tid = threadIdx.x, wave = tid >> 6, lane = tid & 63;

  f32x4 acc[8];
  #pragma unroll
  for (int i = 0; i < 8; ++i) acc[i] = (f32x4){0.f, 0.f, 0.f, 0.f};

  const float* Abase = A + (size_t)b * NN * NN + (size_t)(iblk * 64) * NN;
  const unsigned short* Bbase = HWpT + (size_t)b * FF * NN;
  int ar = tid >> 4, ac = (tid & 15) << 2;  // A staging: 16 rows/pass x 16 thr x 4 f32
  int br = tid >> 3, bc = (tid & 7) << 3;   // B staging: 32 rows/pass x 8 thr x 8 bf16
  int i0g = iblk * 64;
  int mrow = (wave << 4) + (lane & 15);
  int koff = (lane >> 4) << 3;

  for (int k0 = 0; k0 < NN; k0 += 64) {
    // stage A tile (fp32 -> bf16, add identity on diagonal)
    #pragma unroll
    for (int p = 0; p < 4; ++p) {
      int row = ar + (p << 4);
      const float4 v = *reinterpret_cast<const float4*>(Abase + (size_t)row * NN + k0 + ac);
      int gi = i0g + row;
      int gj = k0 + ac;
      float x0 = v.x + ((gi == gj)     ? 1.f : 0.f);
      float x1 = v.y + ((gi == gj + 1) ? 1.f : 0.f);
      float x2 = v.z + ((gi == gj + 2) ? 1.f : 0.f);
      float x3 = v.w + ((gi == gj + 3) ? 1.f : 0.f);
      *reinterpret_cast<unsigned long long*>(&As[row][ac]) = pack4bf(x0, x1, x2, x3);
    }
    // stage B tile (HWpT rows are o, k contiguous -> straight copy)
    #pragma unroll
    for (int p = 0; p < 4; ++p) {
      int row = br + (p << 5);
      *reinterpret_cast<short8*>(&Bs[row][bc]) =
          *reinterpret_cast<const short8*>(Bbase + (size_t)row * NN + k0 + bc);
    }
    __syncthreads();
    #pragma unroll
    for (int kk = 0; kk < 2; ++kk) {
      short8 af = *reinterpret_cast<const short8*>(&As[mrow][(kk << 5) + koff]);
      #pragma unroll
      for (int nf = 0; nf < 8; ++nf) {
        short8 bf = *reinterpret_cast<const short8*>(&Bs[(nf << 4) + (lane & 15)][(kk << 5) + koff]);
        acc[nf] = __builtin_amdgcn_mfma_f32_16x16x32_bf16(af, bf, acc[nf], 0, 0, 0);
      }
    }
    __syncthreads();
  }

  // epilogue: scale rows, +bias, relu, reduce over the block's 64 rows, atomic into pooled
  int irow = i0g + (wave << 4) + ((lane >> 4) << 2);
  float sc0 = isd[(b << 10) + irow];
  float sc1 = isd[(b << 10) + irow + 1];
  float sc2 = isd[(b << 10) + irow + 2];
  float sc3 = isd[(b << 10) + irow + 3];
  #pragma unroll
  for (int nf = 0; nf < 8; ++nf) {
    float bi = bias[(nf << 4) + (lane & 15)];
    float s = fmaxf(acc[nf][0] * sc0 + bi, 0.f)
            + fmaxf(acc[nf][1] * sc1 + bi, 0.f)
            + fmaxf(acc[nf][2] * sc2 + bi, 0.f)
            + fmaxf(acc[nf][3] * sc3 + bi, 0.f);
    s += __shfl_xor(s, 16);
    s += __shfl_xor(s, 32);
    if (lane < 16) atomicAdd(&pooled[(b << 7) + (nf << 4) + lane], s);
  }
}

// ---------------- k5: out[b] = sum_f pooled[b][f]*fc_w[f] + fc_b --------------
__global__ void k5_out(const float* __restrict__ pooled, const float* __restrict__ fcw,
                       const float* __restrict__ fcb, float* __restrict__ out) {
  int b = blockIdx.x, t = threadIdx.x;  // 64 threads
  float s = pooled[(b << 7) + t] * fcw[t] + pooled[(b << 7) + 64 + t] * fcw[64 + t];
  #pragma unroll
  for (int off = 1; off < 64; off <<= 1) s += __shfl_xor(s, off);
  if (t == 0) out[b] = s + fcb[0];
}

extern "C" void kernel_launch(void* const* d_in, const int* in_sizes, int n_in,
                              void* d_out, int out_size, void* d_ws, size_t ws_size,
                              hipStream_t stream) {
  const float* A    = (const float*)d_in[0];
  const float* H    = (const float*)d_in[1];
  const float* W    = (const float*)d_in[2];
  const float* bias = (const float*)d_in[3];
  const float* fcw  = (const float*)d_in[4];
  const float* fcb  = (const float*)d_in[5];
  float* out = (float*)d_out;

  float* ws = (float*)d_ws;
  float* partial = ws;                              // 8*32*1024 = 262144 f32
  float* isd     = ws + 262144;                     // 32768 f32
  float* pooled  = ws + 262144 + 32768;             // 4096 f32
  unsigned short* Wt   = (unsigned short*)(ws + 262144 + 32768 + 4096);  // 16384 bf16
  unsigned short* HWpT = Wt + 16384;                // 32*128*1024 bf16 (8 MB)

  k1_colsum  <<<dim3(4, 8, 32), 256, 0, stream>>>(A, partial);
  k2_finalize<<<128, 256, 0, stream>>>(partial, W, isd, pooled, Wt);
  k3_hw      <<<dim3(8, 32), 512, 0, stream>>>(H, Wt, isd, HWpT);
  k4_gcn     <<<dim3(16, 32), 256, 0, stream>>>(A, HWpT, isd, bias, pooled);
  k5_out     <<<32, 64, 0, stream>>>(pooled, fcw, fcb, out);
}

// Round 2
// 72.591 us; speedup vs baseline: 1.3115x; 1.3115x over previous
//
#include <hip/hip_runtime.h>
#include <hip/hip_bf16.h>

#define NB 32
#define NN 1024
#define FF 128

typedef __attribute__((ext_vector_type(8))) short short8;
typedef __attribute__((ext_vector_type(4))) float f32x4;

static __device__ __forceinline__ unsigned short f2bf(float x) {
  unsigned int u = __float_as_uint(x);
  u += 0x7fffu + ((u >> 16) & 1u);
  return (unsigned short)(u >> 16);
}

static __device__ __forceinline__ unsigned long long pack4bf(float a, float b, float c, float d) {
  return (unsigned long long)f2bf(a)
       | ((unsigned long long)f2bf(b) << 16)
       | ((unsigned long long)f2bf(c) << 32)
       | ((unsigned long long)f2bf(d) << 48);
}

static __device__ __forceinline__ void gl16(const void* g, void* l) {
  __builtin_amdgcn_global_load_lds((const __attribute__((address_space(1))) void*)g,
                                   (__attribute__((address_space(3))) void*)l, 16, 0, 0);
}

// ---- k1: column sums of A + write bf16 Atilde copy (identity added) ----------
// grid (16 i-chunks of 64 rows, 32 b), 256 threads; thread t owns columns 4t..4t+3
__global__ __launch_bounds__(256) void k1_colsum_cvt(const float* __restrict__ A,
                                                     unsigned short* __restrict__ Ab,
                                                     float* __restrict__ partial) {
  int t = threadIdx.x;          // 0..255 -> columns 4t..4t+3
  int s = blockIdx.x;           // 0..15  -> rows s*64..s*64+63
  int b = blockIdx.y;           // 0..31
  const float* base = A + (size_t)b * NN * NN + (size_t)(s * 64) * NN + (t << 2);
  unsigned short* obase = Ab + (size_t)b * NN * NN + (size_t)(s * 64) * NN + (t << 2);
  int jj = t << 2;
  bool diag_band = ((t >> 4) == s);   // diagonal intersects this thread's columns
  float4 sum = make_float4(0.f, 0.f, 0.f, 0.f);
  #pragma unroll 8
  for (int i = 0; i < 64; ++i) {
    float4 v = *reinterpret_cast<const float4*>(base + (size_t)i * NN);
    if (diag_band) {
      int gi = (s << 6) + i;
      v.x += (gi == jj)     ? 1.f : 0.f;
      v.y += (gi == jj + 1) ? 1.f : 0.f;
      v.z += (gi == jj + 2) ? 1.f : 0.f;
      v.w += (gi == jj + 3) ? 1.f : 0.f;
    }
    sum.x += v.x; sum.y += v.y; sum.z += v.z; sum.w += v.w;
    *reinterpret_cast<unsigned long long*>(obase + (size_t)i * NN) =
        pack4bf(v.x, v.y, v.z, v.w);
  }
  *reinterpret_cast<float4*>(partial + (((b << 4) + s) << 10) + jj) = sum;
}

// ---- k2: inv_sqrt_d, zero pooled, Wt = bf16(W^T) -----------------------------
__global__ void k2_finalize(const float* __restrict__ partial, const float* __restrict__ W,
                            float* __restrict__ isd, float* __restrict__ pooled,
                            unsigned short* __restrict__ Wt) {
  int idx = blockIdx.x * 256 + threadIdx.x;  // 0..32767
  int b = idx >> 10, j = idx & 1023;
  float d = 0.0f;   // identity's +1 already inside partial sums (diag added pre-sum)
  #pragma unroll
  for (int s = 0; s < 16; ++s) d += partial[(((b << 4) + s) << 10) + j];
  isd[idx] = rsqrtf(d);
  if (idx < 4096) pooled[idx] = 0.f;
  if (idx < 16384) {
    int o = idx >> 7, k = idx & 127;
    Wt[idx] = f2bf(W[k * FF + o]);   // Wt[o][k] = W[k][o]
  }
}

// ---- k3: HWpT[b][o][j] = bf16( isd[b,j] * sum_k W[k][o]*H[b][j][k] ) ---------
__global__ __launch_bounds__(512) void k3_hw(const float* __restrict__ H,
                                             const unsigned short* __restrict__ Wt,
                                             const float* __restrict__ isd,
                                             unsigned short* __restrict__ HWpT) {
  __shared__ unsigned short Ws[128][136];
  __shared__ unsigned short Hs[128][136];
  int jblk = blockIdx.x;  // 0..7
  int b = blockIdx.y;     // 0..31
  int tid = threadIdx.x, wave = tid >> 6, lane = tid & 63;

  {
    int r = tid >> 4, c = (tid & 15) << 3;
    #pragma unroll
    for (int p = 0; p < 4; ++p) {
      int row = r + (p << 5);
      *reinterpret_cast<short8*>(&Ws[row][c]) =
          *reinterpret_cast<const short8*>(Wt + row * FF + c);
    }
  }
  {
    int r = tid >> 5, c = (tid & 31) << 2;
    const float* Hbase = H + (size_t)b * NN * FF + (size_t)(jblk * 128) * FF;
    #pragma unroll
    for (int p = 0; p < 8; ++p) {
      int row = r + (p << 4);
      const float4 v = *reinterpret_cast<const float4*>(Hbase + (size_t)row * FF + c);
      *reinterpret_cast<unsigned long long*>(&Hs[row][c]) = pack4bf(v.x, v.y, v.z, v.w);
    }
  }
  __syncthreads();

  f32x4 acc[8];
  #pragma unroll
  for (int i = 0; i < 8; ++i) acc[i] = (f32x4){0.f, 0.f, 0.f, 0.f};

  int mrow = (wave << 4) + (lane & 15);
  int koff = (lane >> 4) << 3;
  #pragma unroll
  for (int kk = 0; kk < 4; ++kk) {
    short8 af = *reinterpret_cast<const short8*>(&Ws[mrow][(kk << 5) + koff]);
    #pragma unroll
    for (int nf = 0; nf < 8; ++nf) {
      short8 bf = *reinterpret_cast<const short8*>(&Hs[(nf << 4) + (lane & 15)][(kk << 5) + koff]);
      acc[nf] = __builtin_amdgcn_mfma_f32_16x16x32_bf16(af, bf, acc[nf], 0, 0, 0);
    }
  }

  int fbase = (wave << 4) + ((lane >> 4) << 2);
  #pragma unroll
  for (int nf = 0; nf < 8; ++nf) {
    int j = (jblk << 7) + (nf << 4) + (lane & 15);
    float sc = isd[(b << 10) + j];
    size_t outb = (size_t)b * FF * NN + (size_t)j;
    #pragma unroll
    for (int r = 0; r < 4; ++r) {
      HWpT[outb + (size_t)(fbase + r) * NN] = f2bf(acc[nf][r] * sc);
    }
  }
}

// ---- k4: h = relu(isd_i * (Ab @ HWp')[i,f] + bias_f), fused sum-pool ---------
// bf16 inputs; global_load_lds staging with XOR-swizzled LDS (st_8x16-byte)
__global__ __launch_bounds__(256) void k4_gcn(const unsigned short* __restrict__ Ab,
                                              const unsigned short* __restrict__ HWpT,
                                              const float* __restrict__ isd,
                                              const float* __restrict__ bias,
                                              float* __restrict__ pooled) {
  __shared__ unsigned short As[64 * 64];    // 8 KB, swizzled layout
  __shared__ unsigned short Bs[128 * 64];   // 16 KB, swizzled layout
  int iblk = blockIdx.x;  // 0..15
  int b = blockIdx.y;     // 0..31
  int tid = threadIdx.x, wave = tid >> 6, lane = tid & 63;
  int i0 = iblk * 64;

  f32x4 acc[8];
  #pragma unroll
  for (int i = 0; i < 8; ++i) acc[i] = (f32x4){0.f, 0.f, 0.f, 0.f};

  // staging geometry: wave-uniform LDS base + lane*16 (linear); source chunk
  // pre-swizzled so that read-side XOR sees the right data.
  // row within 8-row stripe == lane>>3 for every 1KB stage, so:
  int schunk = (lane & 7) ^ (lane >> 3);
  int arow = (wave << 4) + (lane >> 3);                  // + p*8, p in {0,1}
  int brow = (wave << 5) + (lane >> 3);                  // + p*8, p in {0..3}
  const unsigned short* aSrc = Ab + (size_t)b * NN * NN + (size_t)(i0 + arow) * NN + (schunk << 3);
  const unsigned short* bSrc = HWpT + (size_t)b * FF * NN + (size_t)brow * NN + (schunk << 3);
  char* asBase = (char*)As + wave * 2048;
  char* bsBase = (char*)Bs + wave * 4096;

  int mrow = (wave << 4) + (lane & 15);
  int q16 = (lane >> 4) << 4;   // byte offset within the 64B k-slice
  int aoff0 = (mrow * 128 + q16) ^ ((mrow & 7) << 4);

  for (int k0 = 0; k0 < NN; k0 += 64) {
    gl16(aSrc,               asBase);
    gl16(aSrc + 8 * NN,      asBase + 1024);
    gl16(bSrc,               bsBase);
    gl16(bSrc + 8 * NN,      bsBase + 1024);
    gl16(bSrc + 16 * NN,     bsBase + 2048);
    gl16(bSrc + 24 * NN,     bsBase + 3072);
    __syncthreads();
    #pragma unroll
    for (int kk = 0; kk < 2; ++kk) {
      const short8 af = *reinterpret_cast<const short8*>((const char*)As + (aoff0 ^ (kk << 6)));
      #pragma unroll
      for (int nf = 0; nf < 8; ++nf) {
        int br = (nf << 4) + (lane & 15);
        const short8 bf = *reinterpret_cast<const short8*>(
            (const char*)Bs + ((br * 128 + kk * 64 + q16) ^ ((br & 7) << 4)));
        acc[nf] = __builtin_amdgcn_mfma_f32_16x16x32_bf16(af, bf, acc[nf], 0, 0, 0);
      }
    }
    __syncthreads();
    aSrc += 64; bSrc += 64;
  }

  // epilogue: scale rows, +bias, relu, column-sum over 64 rows, atomic into pooled
  int irow = i0 + (wave << 4) + ((lane >> 4) << 2);
  float sc0 = isd[(b << 10) + irow];
  float sc1 = isd[(b << 10) + irow + 1];
  float sc2 = isd[(b << 10) + irow + 2];
  float sc3 = isd[(b << 10) + irow + 3];
  #pragma unroll
  for (int nf = 0; nf < 8; ++nf) {
    float bi = bias[(nf << 4) + (lane & 15)];
    float s = fmaxf(acc[nf][0] * sc0 + bi, 0.f)
            + fmaxf(acc[nf][1] * sc1 + bi, 0.f)
            + fmaxf(acc[nf][2] * sc2 + bi, 0.f)
            + fmaxf(acc[nf][3] * sc3 + bi, 0.f);
    s += __shfl_xor(s, 16);
    s += __shfl_xor(s, 32);
    if (lane < 16) atomicAdd(&pooled[(b << 7) + (nf << 4) + lane], s);
  }
}

// ---- k5: out[b] = sum_f pooled[b][f]*fc_w[f] + fc_b --------------------------
__global__ void k5_out(const float* __restrict__ pooled, const float* __restrict__ fcw,
                       const float* __restrict__ fcb, float* __restrict__ out) {
  int b = blockIdx.x, t = threadIdx.x;  // 64 threads
  float s = pooled[(b << 7) + t] * fcw[t] + pooled[(b << 7) + 64 + t] * fcw[64 + t];
  #pragma unroll
  for (int off = 1; off < 64; off <<= 1) s += __shfl_xor(s, off);
  if (t == 0) out[b] = s + fcb[0];
}

extern "C" void kernel_launch(void* const* d_in, const int* in_sizes, int n_in,
                              void* d_out, int out_size, void* d_ws, size_t ws_size,
                              hipStream_t stream) {
  const float* A    = (const float*)d_in[0];
  const float* H    = (const float*)d_in[1];
  const float* W    = (const float*)d_in[2];
  const float* bias = (const float*)d_in[3];
  const float* fcw  = (const float*)d_in[4];
  const float* fcb  = (const float*)d_in[5];
  float* out = (float*)d_out;

  float* ws = (float*)d_ws;
  float* partial = ws;                                   // 16*32*1024 = 524288 f32 (2 MB)
  float* isd     = ws + 524288;                          // 32768 f32
  float* pooled  = ws + 524288 + 32768;                  // 4096 f32
  unsigned short* Wt   = (unsigned short*)(ws + 524288 + 32768 + 4096);   // 16384 bf16
  unsigned short* HWpT = Wt + 16384;                     // 32*128*1024 bf16 (8 MB)
  unsigned short* Ab   = HWpT + (size_t)NB * FF * NN;    // 32*1024*1024 bf16 (64 MB)

  k1_colsum_cvt<<<dim3(16, 32), 256, 0, stream>>>(A, Ab, partial);
  k2_finalize  <<<128, 256, 0, stream>>>(partial, W, isd, pooled, Wt);
  k3_hw        <<<dim3(8, 32), 512, 0, stream>>>(H, Wt, isd, HWpT);
  k4_gcn       <<<dim3(16, 32), 256, 0, stream>>>(Ab, HWpT, isd, bias, pooled);
  k5_out       <<<32, 64, 0, stream>>>(pooled, fcw, fcb, out);
}